// Round 1
// baseline (167.350 us; speedup 1.0000x reference)
//
#include <hip/hip_runtime.h>

#define BS 1024
#define D 128
#define NC 100000
#define NCP 100096           /* padded to 782*128 */
#define NTILES 782
#define S_SCALE 30.0f
#define MARGIN 0.35f
#define GRIDX 64             /* tile-phase blocks; 64*8 = 512 = 2 blocks/CU exactly */
#define S2LOG2E 43.2808512f  /* 30 * log2(e): exp(30c-30) == exp2(fma(c,S2,-S2)) */

typedef __attribute__((ext_vector_type(8))) short bf16x8;
typedef __attribute__((ext_vector_type(4))) float f32x4;

__device__ __forceinline__ unsigned short f2bf(float f) {
    union { float f; unsigned u; } x; x.f = f;
    unsigned u = x.u;
    u += 0x7FFFu + ((u >> 16) & 1u);   // round-to-nearest-even
    return (unsigned short)(u >> 16);
}

// Async global->LDS, 16B per lane. Dest is wave-uniform base; HW adds lane*16.
__device__ __forceinline__ void gld_lds16(const void* g, void* l) {
    auto gp = (const __attribute__((address_space(1))) unsigned int*)(g);
    auto lp = (__attribute__((address_space(3))) unsigned int*)(l);
    __builtin_amdgcn_global_load_lds(gp, lp, 16, 0, 0);
}

// One wave per input row: l2-normalize, emit f32 + swizzled bf16, count labels,
// and compute pos[row] = S * dot(fn, l2norm(weight[label])) exactly in f32.
__global__ void prep_fn(const float* __restrict__ inp, const int* __restrict__ label,
                        const float* __restrict__ wt,
                        float* __restrict__ fn_f32, unsigned short* __restrict__ fn_sw,
                        float* __restrict__ counts, float* __restrict__ pos) {
    int row = blockIdx.x;
    int lane = threadIdx.x;  // blockDim = 64
    float2 v = *(const float2*)(inp + row * D + lane * 2);
    float s = v.x * v.x + v.y * v.y;
    #pragma unroll
    for (int m = 1; m < 64; m <<= 1) s += __shfl_xor(s, m);
    float inv = 1.0f / fmaxf(sqrtf(s), 1e-12f);
    float a = v.x * inv, b = v.y * inv;
    *(float2*)(fn_f32 + row * D + lane * 2) = make_float2(a, b);
    // swizzled bf16: granule g=lane>>2 -> slot g^(row&15); 4B per lane within granule
    unsigned pack = (unsigned)f2bf(a) | ((unsigned)f2bf(b) << 16);
    ((unsigned*)fn_sw)[row * 64 + (((lane >> 2) ^ (row & 15)) << 2) + (lane & 3)] = pack;

    // pos: exact f32 cosine with the label's normalized weight row
    int c = label[row];
    float2 wv = *(const float2*)(wt + c * D + lane * 2);
    float sw_ = wv.x * wv.x + wv.y * wv.y;
    float dt  = wv.x * a + wv.y * b;
    #pragma unroll
    for (int m = 1; m < 64; m <<= 1) { sw_ += __shfl_xor(sw_, m); dt += __shfl_xor(dt, m); }
    if (lane == 0) {
        float invw = 1.0f / fmaxf(sqrtf(sw_), 1e-12f);
        pos[row] = S_SCALE * dt * invw;
        atomicAdd(counts + c, 1.0f);
    }
}

// 4 waves/block, one weight row per wave: l2-normalize -> swizzled bf16 global.
// Fused: write weight output (copy if class absent, 0 if present). Pad rows -> 0.
__global__ void prep_wn(const float* __restrict__ wt, const float* __restrict__ counts,
                        unsigned short* __restrict__ wn_sw, float* __restrict__ outw) {
    int wv = threadIdx.x >> 6, lane = threadIdx.x & 63;
    int row = blockIdx.x * 4 + wv;      // grid 25024 -> 100096 incl. pad
    int t = row >> 7, c = row & 127;
    unsigned* dst = (unsigned*)wn_sw + t * 8192 + c * 64 +
                    (((lane >> 2) ^ (c & 15)) << 2) + (lane & 3);
    if (row < NC) {
        float2 v = *(const float2*)(wt + row * D + lane * 2);
        float s = v.x * v.x + v.y * v.y;
        #pragma unroll
        for (int m = 1; m < 64; m <<= 1) s += __shfl_xor(s, m);
        float inv = 1.0f / fmaxf(sqrtf(s), 1e-12f);
        *dst = (unsigned)f2bf(v.x * inv) | ((unsigned)f2bf(v.y * inv) << 16);
        float cnt = counts[row];
        float2 o = (cnt > 0.0f) ? make_float2(0.0f, 0.0f) : v;
        *(float2*)(outw + row * D + lane * 2) = o;
    } else {
        *dst = 0u;   // pad classes: zero vector -> logit 0 -> e^-30, negligible
    }
}

// Main fused GEMM + exp-accumulate. Block = 256 thr (4 waves, 2x2 over 128x128 tile).
// v2: A fragments hoisted to registers (read once from LDS); B double-buffered with
// one-tile-ahead prefetch via global_load_lds so the vmcnt(0)-before-barrier drain
// overlaps with MFMA+epilogue instead of sitting on the critical path (T3 2-phase).
__global__ __launch_bounds__(256, 2) void main_gemm(
    const unsigned short* __restrict__ fnsw, const unsigned short* __restrict__ wnsw,
    float* __restrict__ sumexp) {
    __shared__ __align__(16) short Bs[2][128 * 128];  // 2 x 32 KB double buffer
    int tid = threadIdx.x;
    int lane = tid & 63, w = tid >> 6;
    int quad = lane >> 4, l15 = lane & 15;
    int m0 = (w >> 1) * 64, n0 = (w & 1) * 64;
    int rowbase = blockIdx.y * 128;   // 8 row tiles cover 1024 rows

    // Stage A once into Bs[0] (transient use), then hoist fragments to registers.
    {
        const char* gA = (const char*)fnsw + rowbase * 256 + w * 8192 + lane * 16;
        char* lA = (char*)Bs[0] + w * 8192;
        #pragma unroll
        for (int j = 0; j < 8; j++) gld_lds16(gA + j * 1024, lA + j * 1024);
    }
    __syncthreads();   // staging drained (compiler emits vmcnt(0) before barrier)

    bf16x8 af[4][4];   // [ks][mt] — 64 VGPRs, live for the whole kernel
    #pragma unroll
    for (int ks = 0; ks < 4; ks++) {
        int kb = ks * 4 + quad;
        #pragma unroll
        for (int mt = 0; mt < 4; mt++) {
            int row = m0 + mt * 16 + l15;          // row&15 == l15
            af[ks][mt] = *(const bf16x8*)(&Bs[0][0] + (row * 16 + (kb ^ l15)) * 8);
        }
    }
    __syncthreads();   // all waves done reading A before Bs[0] is reused for B

    float sums[16];
    #pragma unroll
    for (int i = 0; i < 16; i++) sums[i] = 0.0f;

    // Prologue: stage first B tile into buf 0.
    {
        const char* gB = (const char*)wnsw + blockIdx.x * 32768 + w * 8192 + lane * 16;
        char* lB = (char*)Bs[0] + w * 8192;
        #pragma unroll
        for (int j = 0; j < 8; j++) gld_lds16(gB + j * 1024, lB + j * 1024);
    }
    __syncthreads();   // tile 0 resident

    int cur = 0;
    for (int tile = blockIdx.x; tile < NTILES; tile += GRIDX) {
        // Prefetch next tile into the other buffer; its vmcnt(0) drain happens at
        // the end-of-iteration barrier, fully overlapped with MFMA + epilogue.
        int nxt = tile + GRIDX;
        if (nxt < NTILES) {
            const char* gB = (const char*)wnsw + nxt * 32768 + w * 8192 + lane * 16;
            char* lB = (char*)Bs[cur ^ 1] + w * 8192;
            #pragma unroll
            for (int j = 0; j < 8; j++) gld_lds16(gB + j * 1024, lB + j * 1024);
        }

        f32x4 acc[4][4];
        #pragma unroll
        for (int mt = 0; mt < 4; mt++)
            #pragma unroll
            for (int nt = 0; nt < 4; nt++)
                acc[mt][nt] = (f32x4){0.0f, 0.0f, 0.0f, 0.0f};

        const short* B = &Bs[cur][0];
        #pragma unroll
        for (int ks = 0; ks < 4; ks++) {
            int kb = ks * 4 + quad;
            bf16x8 bf[4];
            #pragma unroll
            for (int nt = 0; nt < 4; nt++) {
                int row = n0 + nt * 16 + l15;
                bf[nt] = *(const bf16x8*)(B + (row * 16 + (kb ^ l15)) * 8);
            }
            #pragma unroll
            for (int mt = 0; mt < 4; mt++)
                #pragma unroll
                for (int nt = 0; nt < 4; nt++)
                    acc[mt][nt] = __builtin_amdgcn_mfma_f32_16x16x32_bf16(
                        af[ks][mt], bf[nt], acc[mt][nt], 0, 0, 0);
        }

        // Epilogue: exp(30c - 30) == exp2(fma(c, 30*log2e, -30*log2e)) — one fma,
        // one v_exp_f32, one add per value.
        #pragma unroll
        for (int nt = 0; nt < 4; nt++)
            #pragma unroll
            for (int mt = 0; mt < 4; mt++)
                #pragma unroll
                for (int r = 0; r < 4; r++)
                    sums[mt * 4 + r] +=
                        __builtin_amdgcn_exp2f(fmaf(acc[mt][nt][r], S2LOG2E, -S2LOG2E));

        __syncthreads();   // drains prefetch (vmcnt 0) + all Bs[cur] reads (lgkmcnt)
        cur ^= 1;
    }

    // Reduce partials across the 16 lanes of each quad, one atomic per row per block.
    #pragma unroll
    for (int mt = 0; mt < 4; mt++) {
        #pragma unroll
        for (int r = 0; r < 4; r++) {
            float s = sums[mt * 4 + r];
            s += __shfl_xor(s, 1);
            s += __shfl_xor(s, 2);
            s += __shfl_xor(s, 4);
            s += __shfl_xor(s, 8);
            if (l15 == 0)
                atomicAdd(sumexp + rowbase + m0 + mt * 16 + quad * 4 + r, s);
        }
    }
}

// loss = mean softplus(M + 30 + log(sum_all - exp(pos-30)) - pos)
__global__ void loss_k(const float* __restrict__ sumexp, const float* __restrict__ pos,
                       float* __restrict__ out) {
    __shared__ float red[256];
    int t = threadIdx.x;
    float acc = 0.0f;
    #pragma unroll
    for (int i = 0; i < 4; i++) {
        int r = t + i * 256;
        float p = pos[r];
        float sneg = fmaxf(sumexp[r] - __expf(p - 30.0f), 1e-38f);
        float lse = 30.0f + logf(sneg);
        float z = MARGIN + lse - p;
        acc += fmaxf(z, 0.0f) + log1pf(__expf(-fabsf(z)));
    }
    red[t] = acc;
    __syncthreads();
    for (int s = 128; s > 0; s >>= 1) {
        if (t < s) red[t] += red[t + s];
        __syncthreads();
    }
    if (t == 0) out[0] = red[0] * (1.0f / 1024.0f);
}

__global__ void addmean_k(const float* __restrict__ fn_f32, const int* __restrict__ label,
                          const float* __restrict__ counts, float* __restrict__ outw) {
    int b = blockIdx.x, t = threadIdx.x;  // 1024 x 128
    int c = label[b];
    float cnt = counts[c];
    atomicAdd(outw + c * D + t, fn_f32[b * D + t] / cnt);
}

extern "C" void kernel_launch(void* const* d_in, const int* in_sizes, int n_in,
                              void* d_out, int out_size, void* d_ws, size_t ws_size,
                              hipStream_t stream) {
    (void)in_sizes; (void)n_in; (void)out_size; (void)ws_size;
    const float* inp   = (const float*)d_in[0];
    const int*   label = (const int*)d_in[1];
    const float* wt    = (const float*)d_in[2];
    float* out = (float*)d_out;

    char* w = (char*)d_ws;
    float*          fn_f32 = (float*)(w);                     // 524288 B
    unsigned short* fn_sw  = (unsigned short*)(w + 524288);   // 262144 B
    unsigned short* wn_sw  = (unsigned short*)(w + 786432);   // 25624576 B
    float*          sumexp = (float*)(w + 26411008);          // 4096 B
    float*          counts = (float*)(w + 26415104);          // 400000 B
    float*          pos    = (float*)(w + 26815104);          // 4096 B

    // zero sumexp + counts (contiguous)
    hipMemsetAsync(w + 26411008, 0, 404096, stream);

    prep_fn<<<BS, 64, 0, stream>>>(inp, label, wt, fn_f32, fn_sw, counts, pos);
    prep_wn<<<NCP / 4, 256, 0, stream>>>(wt, counts, wn_sw, out + 1);
    main_gemm<<<dim3(GRIDX, 8), 256, 0, stream>>>(fn_sw, wn_sw, sumexp);
    addmean_k<<<BS, D, 0, stream>>>(fn_f32, label, counts, out + 1);
    loss_k<<<1, 256, 0, stream>>>(sumexp, pos, out);
}

// Round 2
// 157.513 us; speedup vs baseline: 1.0624x; 1.0624x over previous
//
#include <hip/hip_runtime.h>

#define BS 1024
#define D 128
#define NC 100000
#define NCP 100096           /* padded to 782*128 */
#define NTILES 782
#define S_SCALE 30.0f
#define MARGIN 0.35f
#define GRIDX 48             /* tile phases; 48*16 = 768 blocks = 3/CU exactly */
#define GRIDY 16             /* 64-row slices of the 1024 inputs */
#define S2LOG2E 43.2808512f  /* 30 * log2(e): exp(30c-30) == exp2(fma(c,S2,-S2)) */

typedef __attribute__((ext_vector_type(8))) short bf16x8;
typedef __attribute__((ext_vector_type(4))) float f32x4;

__device__ __forceinline__ unsigned short f2bf(float f) {
    union { float f; unsigned u; } x; x.f = f;
    unsigned u = x.u;
    u += 0x7FFFu + ((u >> 16) & 1u);   // round-to-nearest-even
    return (unsigned short)(u >> 16);
}

// Fragment-sequential bf16 layout (no LDS anywhere -> no bank swizzle):
//   u32 index for (row r, lane l holding k=2l,2l+1):
//     (r>>4)*1024 + (l>>2)*64 + (r&15)*4 + (l&3)
// A wave frag-load (16 rows x one k-granule-quad) is then a CONTIGUOUS 1KB:
//     byte = (r_block)*4096 + ks*1024 + lane*16

// One wave per input row: l2-normalize, emit f32 + frag-layout bf16, count labels,
// and compute pos[row] = S * dot(fn, l2norm(weight[label])) exactly in f32.
__global__ void prep_fn(const float* __restrict__ inp, const int* __restrict__ label,
                        const float* __restrict__ wt,
                        float* __restrict__ fn_f32, unsigned short* __restrict__ fn_fr,
                        float* __restrict__ counts, float* __restrict__ pos) {
    int row = blockIdx.x;
    int lane = threadIdx.x;  // blockDim = 64
    float2 v = *(const float2*)(inp + row * D + lane * 2);
    float s = v.x * v.x + v.y * v.y;
    #pragma unroll
    for (int m = 1; m < 64; m <<= 1) s += __shfl_xor(s, m);
    float inv = 1.0f / fmaxf(sqrtf(s), 1e-12f);
    float a = v.x * inv, b = v.y * inv;
    *(float2*)(fn_f32 + row * D + lane * 2) = make_float2(a, b);
    unsigned pack = (unsigned)f2bf(a) | ((unsigned)f2bf(b) << 16);
    ((unsigned*)fn_fr)[(row >> 4) * 1024 + (lane >> 2) * 64 + ((row & 15) << 2) + (lane & 3)] = pack;

    // pos: exact f32 cosine with the label's normalized weight row
    int c = label[row];
    float2 wv = *(const float2*)(wt + c * D + lane * 2);
    float sw_ = wv.x * wv.x + wv.y * wv.y;
    float dt  = wv.x * a + wv.y * b;
    #pragma unroll
    for (int m = 1; m < 64; m <<= 1) { sw_ += __shfl_xor(sw_, m); dt += __shfl_xor(dt, m); }
    if (lane == 0) {
        float invw = 1.0f / fmaxf(sqrtf(sw_), 1e-12f);
        pos[row] = S_SCALE * dt * invw;
        atomicAdd(counts + c, 1.0f);
    }
}

// 4 waves/block, one weight row per wave: l2-normalize -> frag-layout bf16 global.
// Fused: write weight output (copy if class absent, 0 if present). Pad rows -> 0.
__global__ void prep_wn(const float* __restrict__ wt, const float* __restrict__ counts,
                        unsigned short* __restrict__ wn_fr, float* __restrict__ outw) {
    int wv = threadIdx.x >> 6, lane = threadIdx.x & 63;
    int row = blockIdx.x * 4 + wv;      // grid 25024 -> 100096 incl. pad
    unsigned* dst = (unsigned*)wn_fr + (row >> 4) * 1024 + (lane >> 2) * 64 +
                    ((row & 15) << 2) + (lane & 3);
    if (row < NC) {
        float2 v = *(const float2*)(wt + row * D + lane * 2);
        float s = v.x * v.x + v.y * v.y;
        #pragma unroll
        for (int m = 1; m < 64; m <<= 1) s += __shfl_xor(s, m);
        float inv = 1.0f / fmaxf(sqrtf(s), 1e-12f);
        *dst = (unsigned)f2bf(v.x * inv) | ((unsigned)f2bf(v.y * inv) << 16);
        float cnt = counts[row];
        float2 o = (cnt > 0.0f) ? make_float2(0.0f, 0.0f) : v;
        *(float2*)(outw + row * D + lane * 2) = o;
    } else {
        *dst = 0u;   // pad classes: zero vector -> logit 0 -> e^-30, negligible
    }
}

// Main fused GEMM + exp-accumulate. v3: NO LDS staging, NO barriers in the loop.
// Block = 256 thr (4 waves); block tile 64 rows x 128 cols; wave = 64 rows x 32 cols
// (its B fragments are private -> B streams global->reg, coalesced 1KB loads; the
// 16 y-blocks sharing a B tile all land on one XCD (48*dy % 8 == 0) -> L2 serves
// the reuse). A (64 rows) hoisted to 64 VGPRs once. 3 blocks/CU (12 waves, VGPR-
// capped), loads for tile t+1 issued between MFMA and exp-epilogue (T14).
__global__ __launch_bounds__(256, 3) void main_gemm(
    const unsigned short* __restrict__ fnfr, const unsigned short* __restrict__ wnfr,
    float* __restrict__ sumexp) {
    __shared__ float red[256];
    int tid = threadIdx.x;
    int lane = tid & 63, w = tid >> 6;
    int quad = lane >> 4, l15 = lane & 15;
    int rowbase = blockIdx.y * 64;

    // A fragments: 16 contiguous 1KB wave-loads, resident for the whole kernel.
    bf16x8 af[4][4];   // [ks][mt]
    {
        const char* gA = (const char*)fnfr + (rowbase >> 4) * 4096 + lane * 16;
        #pragma unroll
        for (int mt = 0; mt < 4; mt++)
            #pragma unroll
            for (int ks = 0; ks < 4; ks++)
                af[ks][mt] = *(const bf16x8*)(gA + mt * 4096 + ks * 1024);
    }

    float sums[16];
    #pragma unroll
    for (int i = 0; i < 16; i++) sums[i] = 0.0f;

    // wave's B base: col-block (tile*8 + w*2 + nt), bytes (cb*4096 + ks*1024 + lane*16)
    const char* gB = (const char*)wnfr + (size_t)blockIdx.x * 32768 + w * 8192 + lane * 16;
    const long long step = (long long)GRIDX * 32768;

    bf16x8 b[2][4];    // [nt][ks] — single set, reloaded (WAR) after last MFMA use
    #pragma unroll
    for (int nt = 0; nt < 2; nt++)
        #pragma unroll
        for (int ks = 0; ks < 4; ks++)
            b[nt][ks] = *(const bf16x8*)(gB + nt * 4096 + ks * 1024);

    for (int tile = blockIdx.x; tile < NTILES; tile += GRIDX) {
        f32x4 acc[4][2];
        #pragma unroll
        for (int mt = 0; mt < 4; mt++)
            #pragma unroll
            for (int nt = 0; nt < 2; nt++)
                acc[mt][nt] = (f32x4){0.0f, 0.0f, 0.0f, 0.0f};

        #pragma unroll
        for (int ks = 0; ks < 4; ks++)
            #pragma unroll
            for (int mt = 0; mt < 4; mt++)
                #pragma unroll
                for (int nt = 0; nt < 2; nt++)
                    acc[mt][nt] = __builtin_amdgcn_mfma_f32_16x16x32_bf16(
                        af[ks][mt], b[nt][ks], acc[mt][nt], 0, 0, 0);

        // Issue next tile's loads NOW (b regs dead after the MFMAs above); the
        // exp epilogue below covers the L2 latency before next iteration's waits.
        gB += step;
        if (tile + GRIDX < NTILES) {
            #pragma unroll
            for (int nt = 0; nt < 2; nt++)
                #pragma unroll
                for (int ks = 0; ks < 4; ks++)
                    b[nt][ks] = *(const bf16x8*)(gB + nt * 4096 + ks * 1024);
        }

        // exp(30c - 30) == exp2(fma(c, 30*log2e, -30*log2e))
        #pragma unroll
        for (int mt = 0; mt < 4; mt++)
            #pragma unroll
            for (int nt = 0; nt < 2; nt++)
                #pragma unroll
                for (int r = 0; r < 4; r++)
                    sums[mt * 4 + r] +=
                        __builtin_amdgcn_exp2f(fmaf(acc[mt][nt][r], S2LOG2E, -S2LOG2E));
    }

    // Reduce across the 16 lanes of each quad, then across the 4 waves via LDS:
    // one atomic per row per block (64 atomics/block).
    #pragma unroll
    for (int mt = 0; mt < 4; mt++) {
        #pragma unroll
        for (int r = 0; r < 4; r++) {
            float s = sums[mt * 4 + r];
            s += __shfl_xor(s, 1);
            s += __shfl_xor(s, 2);
            s += __shfl_xor(s, 4);
            s += __shfl_xor(s, 8);
            if (l15 == 0) red[w * 64 + mt * 16 + quad * 4 + r] = s;
        }
    }
    __syncthreads();
    if (tid < 64) {
        float s = red[tid] + red[64 + tid] + red[128 + tid] + red[192 + tid];
        atomicAdd(sumexp + rowbase + tid, s);
    }
}

// loss = mean softplus(M + 30 + log(sum_all - exp(pos-30)) - pos)
__global__ void loss_k(const float* __restrict__ sumexp, const float* __restrict__ pos,
                       float* __restrict__ out) {
    __shared__ float red[256];
    int t = threadIdx.x;
    float acc = 0.0f;
    #pragma unroll
    for (int i = 0; i < 4; i++) {
        int r = t + i * 256;
        float p = pos[r];
        float sneg = fmaxf(sumexp[r] - __expf(p - 30.0f), 1e-38f);
        float lse = 30.0f + logf(sneg);
        float z = MARGIN + lse - p;
        acc += fmaxf(z, 0.0f) + log1pf(__expf(-fabsf(z)));
    }
    red[t] = acc;
    __syncthreads();
    for (int s = 128; s > 0; s >>= 1) {
        if (t < s) red[t] += red[t + s];
        __syncthreads();
    }
    if (t == 0) out[0] = red[0] * (1.0f / 1024.0f);
}

__global__ void addmean_k(const float* __restrict__ fn_f32, const int* __restrict__ label,
                          const float* __restrict__ counts, float* __restrict__ outw) {
    int b = blockIdx.x, t = threadIdx.x;  // 1024 x 128
    int c = label[b];
    float cnt = counts[c];
    atomicAdd(outw + c * D + t, fn_f32[b * D + t] / cnt);
}

extern "C" void kernel_launch(void* const* d_in, const int* in_sizes, int n_in,
                              void* d_out, int out_size, void* d_ws, size_t ws_size,
                              hipStream_t stream) {
    (void)in_sizes; (void)n_in; (void)out_size; (void)ws_size;
    const float* inp   = (const float*)d_in[0];
    const int*   label = (const int*)d_in[1];
    const float* wt    = (const float*)d_in[2];
    float* out = (float*)d_out;

    char* w = (char*)d_ws;
    float*          fn_f32 = (float*)(w);                     // 524288 B
    unsigned short* fn_fr  = (unsigned short*)(w + 524288);   // 262144 B
    unsigned short* wn_fr  = (unsigned short*)(w + 786432);   // 25624576 B
    float*          sumexp = (float*)(w + 26411008);          // 4096 B
    float*          counts = (float*)(w + 26415104);          // 400000 B
    float*          pos    = (float*)(w + 26815104);          // 4096 B

    // zero sumexp + counts (contiguous)
    hipMemsetAsync(w + 26411008, 0, 404096, stream);

    prep_fn<<<BS, 64, 0, stream>>>(inp, label, wt, fn_f32, fn_fr, counts, pos);
    prep_wn<<<NCP / 4, 256, 0, stream>>>(wt, counts, wn_fr, out + 1);
    main_gemm<<<dim3(GRIDX, GRIDY), 256, 0, stream>>>(fn_fr, wn_fr, sumexp);
    addmean_k<<<BS, D, 0, stream>>>(fn_f32, label, counts, out + 1);
    loss_k<<<1, 256, 0, stream>>>(sumexp, pos, out);
}